// Round 11
// baseline (558.391 us; speedup 1.0000x reference)
//
#include <hip/hip_runtime.h>
#include <hip/hip_bf16.h>
#include <math.h>

#define N_NODES 50000
#define N_EDGES 800000
#define NUM_GRAPHS 64
#define NPAD 50048          // multiple of 64
#define KPAD0 288           // 261 padded to multiple of 32
#define PSPLIT 16
#define MAXDEG 64           // Poisson(16): P(deg>64) ~ 1e-20
#define CBAND 16684u        // 3 bands x 16684 >= 50000; window = 2.13 MB < 4 MB L2/XCD

#define GEMM0_GRID (NPAD / 64)                  // 782
#define SCAT_GRID  ((N_EDGES + 255) / 256)      // 3125
#define ZERO_GRID  ((N_NODES + 255) / 256)      // 196
#define PREPW_TOT  (128 * KPAD0 + 6 * 128 * 64) // 86016
#define PREPW_GRID ((PREPW_TOT + 255) / 256)    // 336

typedef __attribute__((ext_vector_type(8))) short short8;
typedef __attribute__((ext_vector_type(4))) float f32x4;

__device__ __forceinline__ float gelu_f(float v) {
    return 0.5f * v * (1.0f + erff(v * 0.70710678118654752440f));
}

__device__ __forceinline__ float half_sum32(float v) {
    v += __shfl_xor(v, 1); v += __shfl_xor(v, 2); v += __shfl_xor(v, 4);
    v += __shfl_xor(v, 8); v += __shfl_xor(v, 16);
    return v;
}

__device__ __forceinline__ float group_sum8(float v) {
    v += __shfl_xor(v, 1); v += __shfl_xor(v, 2); v += __shfl_xor(v, 4);
    return v;
}

__device__ __forceinline__ unsigned short f2bf(float f) {
    unsigned int u = __float_as_uint(f);
    unsigned int r = (u + 0x7fffu + ((u >> 16) & 1u)) >> 16;
    return (unsigned short)r;
}

__device__ __forceinline__ float bf_lo(unsigned int u) {
    return __uint_as_float(u << 16);
}
__device__ __forceinline__ float bf_hi(unsigned int u) {
    return __uint_as_float(u & 0xffff0000u);
}

// ---------------- prep: deg zero + weight transpose ----------------

__global__ void k_prep(int* __restrict__ deg,
                       const float* __restrict__ Wl0, const float* __restrict__ Wr0,
                       const float* __restrict__ Wl, const float* __restrict__ Wr,
                       unsigned short* __restrict__ Bt0, unsigned short* __restrict__ BtR) {
    const int blk = blockIdx.x, tid = threadIdx.x;
    if (blk < ZERO_GRID) {
        int i = blk * 256 + tid;
        if (i < N_NODES) deg[i] = 0;
        return;
    }
    int idx = (blk - ZERO_GRID) * 256 + tid;
    const int n0 = 128 * KPAD0;
    if (idx < n0) {
        int j = idx / KPAD0, k = idx - j * KPAD0;
        float v = 0.0f;
        if (k < 261) v = (j < 64) ? Wl0[k * 64 + j] : Wr0[k * 64 + (j - 64)];
        Bt0[idx] = f2bf(v);
    } else if (idx < PREPW_TOT) {
        int r = idx - n0;
        int l = r >> 13;
        int rr = r & 8191;
        int j = rr >> 6, k = rr & 63;
        float v = (j < 64) ? Wl[l * 4096 + k * 64 + j] : Wr[l * 4096 + k * 64 + (j - 64)];
        BtR[r] = f2bf(v);
    }
}

// ---------------- fused front: mgemm0 | scatf (mutually independent) ----------------

__global__ __launch_bounds__(256) void k_front(
        const float* __restrict__ X, const unsigned short* __restrict__ Bt0,
        unsigned short* __restrict__ U, float* __restrict__ V,
        const int* __restrict__ src, const int* __restrict__ dst,
        int* __restrict__ deg, unsigned short* __restrict__ col64) {
    __shared__ __align__(16) unsigned short sA[64 * 32];
    __shared__ __align__(16) unsigned short sB[128 * 32];
    const int blk = blockIdx.x;
    const int tid = threadIdx.x;

    if (blk < GEMM0_GRID) {
        const int lane = tid & 63, wid = tid >> 6;
        const int l16 = lane & 15, quad = lane >> 4;
        const int m0 = blk * 64;
        f32x4 acc[8];
        #pragma unroll
        for (int j = 0; j < 8; ++j) { acc[j][0] = 0.f; acc[j][1] = 0.f; acc[j][2] = 0.f; acc[j][3] = 0.f; }
        const int arow = tid >> 2, apart = (tid & 3) << 3;
        const int node = m0 + arow;
        const int rowok = (node < N_NODES);
        for (int kc = 0; kc < KPAD0; kc += 32) {
            if (kc) __syncthreads();
            short8 av;
            #pragma unroll
            for (int j = 0; j < 8; ++j) {
                int kk = kc + apart + j;
                float val = (rowok && kk < 261) ? X[(size_t)node * 261 + kk] : 0.0f;
                av[j] = (short)f2bf(val);
            }
            *(short8*)&sA[arow * 32 + apart] = av;
            #pragma unroll
            for (int q = 0; q < 2; ++q) {
                int flat = q * 256 + tid;
                int br = flat >> 2, bp = (flat & 3) << 3;
                *(int4*)&sB[br * 32 + bp] = *(const int4*)&Bt0[(size_t)br * KPAD0 + kc + bp];
            }
            __syncthreads();
            short8 af = *(const short8*)&sA[(wid * 16 + l16) * 32 + quad * 8];
            #pragma unroll
            for (int j = 0; j < 8; ++j) {
                short8 bf = *(const short8*)&sB[(j * 16 + l16) * 32 + quad * 8];
                acc[j] = __builtin_amdgcn_mfma_f32_16x16x32_bf16(af, bf, acc[j], 0, 0, 0);
            }
        }
        const int rbase = m0 + wid * 16 + quad * 4;
        #pragma unroll
        for (int j = 0; j < 4; ++j)
            #pragma unroll
            for (int r = 0; r < 4; ++r)
                U[(size_t)(rbase + r) * 64 + j * 16 + l16] = f2bf(acc[j][r]);
        #pragma unroll
        for (int j = 4; j < 8; ++j)
            #pragma unroll
            for (int r = 0; r < 4; ++r)
                V[(size_t)(rbase + r) * 64 + (j - 4) * 16 + l16] = acc[j][r];
    } else {
        int i = (blk - GEMM0_GRID) * 256 + tid;
        if (i < N_EDGES) {
            int d = dst[i];
            int pos = atomicAdd(&deg[d], 1);
            if (pos < MAXDEG) col64[(d << 6) + pos] = (unsigned short)src[i];
        }
    }
}

// ---------------- fused layer: aggln(layer i) + mgemm(layer i+1) ----------------
// Gather is column-banded (3 bands x 2.13 MB window): all 782 blocks are
// co-resident, so each XCD's L2 serves in-band gathers; LLC refills the
// window once per band instead of thrashing on the full 6.4 MB U.

__global__ __launch_bounds__(256) void k_layer(
        const unsigned short* __restrict__ U_in, const float* __restrict__ V_in,
        unsigned short* __restrict__ h,            // in-place: residual in, LN out
        float* __restrict__ hf_out,                // last layer: fp32 copy for pooling
        const int* __restrict__ deg, const unsigned short* __restrict__ col64,
        const float* __restrict__ bias, const float* __restrict__ gam,
        const float* __restrict__ bet,
        const unsigned short* __restrict__ Bt_next,
        unsigned short* __restrict__ U_out, float* __restrict__ V_out,
        int residual, int have_gemm) {
    __shared__ __align__(16) unsigned short sA[2 * 64 * 32];  // [chunk][row][32k]
    __shared__ __align__(16) unsigned short sB[128 * 32];
    const int tid = threadIdx.x;
    const int lane = tid & 63, wid = tid >> 6;
    const int sub = lane >> 3, hl = lane & 7;
    const int base = lane & 56;
    const int m0 = blockIdx.x * 64;
    const uint4* __restrict__ Up = (const uint4*)U_in;

    #pragma unroll
    for (int rep = 0; rep < 2; ++rep) {
        const int nl = rep * 32 + wid * 8 + sub;
        const int node = m0 + nl;
        const bool valid = (node < N_NODES);
        const int nd = valid ? node : 0;
        const int dg = valid ? deg[nd] : 0;
        const int cnt = min(dg, MAXDEG);
        uint4 cv = make_uint4(0u, 0u, 0u, 0u);
        if (valid) cv = *(const uint4*)&col64[((size_t)nd << 6) + hl * 8];
        float s0 = 0.f, s1 = 0.f, s2 = 0.f, s3 = 0.f, s4 = 0.f, s5 = 0.f, s6 = 0.f, s7 = 0.f;
        #pragma unroll 1
        for (int pass = 0; pass < 3; ++pass) {
            const unsigned lo = (unsigned)pass * CBAND;
            for (int b = 0; b * 8 < cnt; b += 2) {
                #pragma unroll
                for (int hh = 0; hh < 2; ++hh) {
                    const int sl = base + b + hh;
                    unsigned int p0 = (unsigned int)__shfl((int)cv.x, sl);
                    unsigned int p1 = (unsigned int)__shfl((int)cv.y, sl);
                    unsigned int p2 = (unsigned int)__shfl((int)cv.z, sl);
                    unsigned int p3 = (unsigned int)__shfl((int)cv.w, sl);
                    const int eb = (b + hh) * 8;
                    int c[8];
                    c[0] = (int)(p0 & 0xffffu); c[1] = (int)(p0 >> 16);
                    c[2] = (int)(p1 & 0xffffu); c[3] = (int)(p1 >> 16);
                    c[4] = (int)(p2 & 0xffffu); c[5] = (int)(p2 >> 16);
                    c[6] = (int)(p3 & 0xffffu); c[7] = (int)(p3 >> 16);
                    #pragma unroll
                    for (int i = 0; i < 8; ++i) {
                        bool ok = (eb + i < cnt) && ((unsigned)(c[i] - lo) < CBAND);
                        uint4 u = ok ? Up[(size_t)c[i] * 8 + hl] : make_uint4(0u, 0u, 0u, 0u);
                        s0 += bf_lo(u.x); s1 += bf_hi(u.x);
                        s2 += bf_lo(u.y); s3 += bf_hi(u.y);
                        s4 += bf_lo(u.z); s5 += bf_hi(u.z);
                        s6 += bf_lo(u.w); s7 += bf_hi(u.w);
                    }
                }
            }
        }
        const float id = 1.0f / fmaxf((float)dg, 1.0f);
        const float4 b0 = *(const float4*)&bias[8 * hl];
        const float4 b1 = *(const float4*)&bias[8 * hl + 4];
        float4 v0 = make_float4(0.f, 0.f, 0.f, 0.f), v1 = v0;
        if (valid) {
            v0 = *(const float4*)&V_in[(size_t)nd * 64 + 8 * hl];
            v1 = *(const float4*)&V_in[(size_t)nd * 64 + 8 * hl + 4];
        }
        float f0 = gelu_f(s0 * id + b0.x + v0.x);
        float f1 = gelu_f(s1 * id + b0.y + v0.y);
        float f2 = gelu_f(s2 * id + b0.z + v0.z);
        float f3 = gelu_f(s3 * id + b0.w + v0.w);
        float f4 = gelu_f(s4 * id + b1.x + v1.x);
        float f5 = gelu_f(s5 * id + b1.y + v1.y);
        float f6 = gelu_f(s6 * id + b1.z + v1.z);
        float f7 = gelu_f(s7 * id + b1.w + v1.w);
        float mu = group_sum8(((f0 + f1) + (f2 + f3)) + ((f4 + f5) + (f6 + f7))) * 0.015625f;
        float d0 = f0 - mu, d1 = f1 - mu, d2 = f2 - mu, d3 = f3 - mu;
        float d4 = f4 - mu, d5 = f5 - mu, d6 = f6 - mu, d7 = f7 - mu;
        float var = group_sum8(((d0 * d0 + d1 * d1) + (d2 * d2 + d3 * d3)) +
                               ((d4 * d4 + d5 * d5) + (d6 * d6 + d7 * d7))) * 0.015625f;
        float rs = rsqrtf(var + 1e-5f);
        const float4 g0v = *(const float4*)&gam[8 * hl];
        const float4 g1v = *(const float4*)&gam[8 * hl + 4];
        const float4 e0v = *(const float4*)&bet[8 * hl];
        const float4 e1v = *(const float4*)&bet[8 * hl + 4];
        f0 = d0 * rs * g0v.x + e0v.x;
        f1 = d1 * rs * g0v.y + e0v.y;
        f2 = d2 * rs * g0v.z + e0v.z;
        f3 = d3 * rs * g0v.w + e0v.w;
        f4 = d4 * rs * g1v.x + e1v.x;
        f5 = d5 * rs * g1v.y + e1v.y;
        f6 = d6 * rs * g1v.z + e1v.z;
        f7 = d7 * rs * g1v.w + e1v.w;
        if (residual && valid) {
            uint4 hu = ((const uint4*)h)[(size_t)nd * 8 + hl];
            f0 += bf_lo(hu.x); f1 += bf_hi(hu.x);
            f2 += bf_lo(hu.y); f3 += bf_hi(hu.y);
            f4 += bf_lo(hu.z); f5 += bf_hi(hu.z);
            f6 += bf_lo(hu.w); f7 += bf_hi(hu.w);
        }
        uint4 outw;
        outw.x = (unsigned int)f2bf(f0) | ((unsigned int)f2bf(f1) << 16);
        outw.y = (unsigned int)f2bf(f2) | ((unsigned int)f2bf(f3) << 16);
        outw.z = (unsigned int)f2bf(f4) | ((unsigned int)f2bf(f5) << 16);
        outw.w = (unsigned int)f2bf(f6) | ((unsigned int)f2bf(f7) << 16);
        if (valid) {
            ((uint4*)h)[(size_t)nd * 8 + hl] = outw;
            if (hf_out) {
                *(float4*)&hf_out[(size_t)nd * 64 + 8 * hl] = make_float4(f0, f1, f2, f3);
                *(float4*)&hf_out[(size_t)nd * 64 + 8 * hl + 4] = make_float4(f4, f5, f6, f7);
            }
        }
        // park LN output in LDS as next-GEMM A-tile: chunk=hl>>2, k-offset=(hl&3)*8
        *(uint4*)&sA[(((hl >> 2) * 64 + nl) << 5) + (hl & 3) * 8] = outw;
    }
    if (!have_gemm) return;
    __syncthreads();

    // ---- GEMM: [U_out | V_out](rows m0..m0+63) = sA @ Bt_next, K=64 ----
    const int l16 = lane & 15, quad = lane >> 4;
    f32x4 acc[8];
    #pragma unroll
    for (int j = 0; j < 8; ++j) { acc[j][0] = 0.f; acc[j][1] = 0.f; acc[j][2] = 0.f; acc[j][3] = 0.f; }
    for (int kc = 0; kc < 64; kc += 32) {
        if (kc) __syncthreads();
        #pragma unroll
        for (int q = 0; q < 2; ++q) {
            int flat = q * 256 + tid;
            int br = flat >> 2, bp = (flat & 3) << 3;
            *(int4*)&sB[br * 32 + bp] = *(const int4*)&Bt_next[(size_t)br * 64 + kc + bp];
        }
        __syncthreads();
        short8 af = *(const short8*)&sA[(((kc >> 5) * 64 + wid * 16 + l16) << 5) + quad * 8];
        #pragma unroll
        for (int j = 0; j < 8; ++j) {
            short8 bf = *(const short8*)&sB[(j * 16 + l16) * 32 + quad * 8];
            acc[j] = __builtin_amdgcn_mfma_f32_16x16x32_bf16(af, bf, acc[j], 0, 0, 0);
        }
    }
    const int rbase = m0 + wid * 16 + quad * 4;
    #pragma unroll
    for (int j = 0; j < 4; ++j)
        #pragma unroll
        for (int r = 0; r < 4; ++r)
            U_out[(size_t)(rbase + r) * 64 + j * 16 + l16] = f2bf(acc[j][r]);
    #pragma unroll
    for (int j = 4; j < 8; ++j)
        #pragma unroll
        for (int r = 0; r < 4; ++r)
            V_out[(size_t)(rbase + r) * 64 + (j - 4) * 16 + l16] = acc[j][r];
}

// ---------------- pooling stage 1 ----------------

__global__ __launch_bounds__(256) void k_pool1(const float* __restrict__ h, const int* __restrict__ batch,
                                               float* __restrict__ partial, int n) {
    __shared__ float sred[4][64];
    const int g = blockIdx.x / PSPLIT;
    const int s = blockIdx.x - g * PSPLIT;
    const int lane = threadIdx.x & 63, wid = threadIdx.x >> 6;
    int lo = 0, hi = n;
    while (lo < hi) { int mid = (lo + hi) >> 1; if (batch[mid] < g) lo = mid + 1; else hi = mid; }
    const int start = lo;
    lo = 0; hi = n;
    while (lo < hi) { int mid = (lo + hi) >> 1; if (batch[mid] < g + 1) lo = mid + 1; else hi = mid; }
    const int end = lo;
    const int len = end - start;
    const int chunk = (len + PSPLIT - 1) / PSPLIT;
    const int a = start + s * chunk;
    const int b = min(a + chunk, end);
    float sum = 0.0f;
    for (int node = a + wid; node < b; node += 4) sum += h[(size_t)node * 64 + lane];
    sred[wid][lane] = sum;
    __syncthreads();
    if (wid == 0)
        partial[(size_t)blockIdx.x * 64 + lane] = sred[0][lane] + sred[1][lane] + sred[2][lane] + sred[3][lane];
}

// ---------------- MLP head (folds pool stage 2) ----------------

__global__ __launch_bounds__(1024) void k_head(const float* __restrict__ partial,
                                               const float* __restrict__ M0, const float* __restrict__ mb0,
                                               const float* __restrict__ mg0, const float* __restrict__ mbeta0,
                                               const float* __restrict__ M, const float* __restrict__ mb,
                                               const float* __restrict__ mg, const float* __restrict__ mbeta,
                                               const float* __restrict__ Wf, const float* __restrict__ bf,
                                               float* __restrict__ out) {
    __shared__ float sP[64 * 64];
    __shared__ float sA[64 * 33];
    __shared__ float sB[64 * 33];
    const int tx = threadIdx.x, ty = threadIdx.y;
    const int tid = ty * 32 + tx;
    for (int i = tid; i < 64 * 64; i += 1024) {
        int g = i >> 6, f = i & 63;
        float s = 0.0f;
        #pragma unroll
        for (int s2 = 0; s2 < PSPLIT; ++s2) s += partial[(size_t)(g * PSPLIT + s2) * 64 + f];
        sP[i] = s;
    }
    __syncthreads();
    #pragma unroll
    for (int rr = 0; rr < 2; ++rr) {
        int r = ty + rr * 32;
        float a = mb0[tx];
        for (int k = 0; k < 64; ++k) a += sP[r * 64 + k] * M0[k * 32 + tx];
        a = gelu_f(a);
        float mu = half_sum32(a) * (1.0f / 32.0f);
        float d = a - mu;
        float var = half_sum32(d * d) * (1.0f / 32.0f);
        a = d * rsqrtf(var + 1e-5f) * mg0[tx] + mbeta0[tx];
        sA[r * 33 + tx] = a;
    }
    __syncthreads();
    float* cur = sA;
    float* nxt = sB;
    for (int L = 0; L < 3; ++L) {
        const float* Mi = M + L * 32 * 32;
        const float* mbi = mb + L * 32;
        const float* mgi = mg + L * 32;
        const float* mbetai = mbeta + L * 32;
        #pragma unroll
        for (int rr = 0; rr < 2; ++rr) {
            int r = ty + rr * 32;
            float a = mbi[tx];
            for (int k = 0; k < 32; ++k) a += cur[r * 33 + k] * Mi[k * 32 + tx];
            a = gelu_f(a);
            float mu = half_sum32(a) * (1.0f / 32.0f);
            float d = a - mu;
            float var = half_sum32(d * d) * (1.0f / 32.0f);
            a = d * rsqrtf(var + 1e-5f) * mgi[tx] + mbetai[tx] + cur[r * 33 + tx];
            nxt[r * 33 + tx] = a;
        }
        __syncthreads();
        float* t = cur; cur = nxt; nxt = t;
    }
    #pragma unroll
    for (int rr = 0; rr < 2; ++rr) {
        int r = ty + rr * 32;
        float p = cur[r * 33 + tx] * Wf[tx];
        p = half_sum32(p);
        if (tx == 0) out[r] = p + bf[0];
    }
}

// ---------------- host launcher ----------------

extern "C" void kernel_launch(void* const* d_in, const int* in_sizes, int n_in,
                              void* d_out, int out_size, void* d_ws, size_t ws_size,
                              hipStream_t stream) {
    const int N = N_NODES;
    const int E = N_EDGES;

    const float* x    = (const float*)d_in[0];
    const int* eidx   = (const int*)d_in[1];
    const int* batch  = (const int*)d_in[2];
    const float* Wl0  = (const float*)d_in[3];
    const float* bl0  = (const float*)d_in[4];
    const float* Wr0  = (const float*)d_in[5];
    const float* g0   = (const float*)d_in[6];
    const float* bet0 = (const float*)d_in[7];
    const float* Wl   = (const float*)d_in[8];
    const float* bl   = (const float*)d_in[9];
    const float* Wr   = (const float*)d_in[10];
    const float* gR   = (const float*)d_in[11];
    const float* betR = (const float*)d_in[12];
    const float* M0   = (const float*)d_in[13];
    const float* mb0  = (const float*)d_in[14];
    const float* mg0  = (const float*)d_in[15];
    const float* mbe0 = (const float*)d_in[16];
    const float* M    = (const float*)d_in[17];
    const float* mb   = (const float*)d_in[18];
    const float* mg   = (const float*)d_in[19];
    const float* mbe  = (const float*)d_in[20];
    const float* Wf   = (const float*)d_in[21];
    const float* bf   = (const float*)d_in[22];

    const int* src = eidx;
    const int* dst = eidx + E;

    char* p = (char*)d_ws;
    auto alloc = [&](size_t bytes) -> void* {
        void* q = (void*)p;
        p += (bytes + 255) & ~(size_t)255;
        return q;
    };
    int*   deg    = (int*)alloc((size_t)N * 4);
    unsigned short* col64 = (unsigned short*)alloc((size_t)N * MAXDEG * 2);
    unsigned short* Bt0 = (unsigned short*)alloc((size_t)128 * KPAD0 * 2);
    unsigned short* BtR = (unsigned short*)alloc((size_t)6 * 128 * 64 * 2);
    unsigned short* Ua  = (unsigned short*)alloc((size_t)NPAD * 64 * 2);
    unsigned short* Ub  = (unsigned short*)alloc((size_t)NPAD * 64 * 2);
    float* Va   = (float*)alloc((size_t)NPAD * 64 * 4);
    float* Vb   = (float*)alloc((size_t)NPAD * 64 * 4);
    unsigned short* hbuf = (unsigned short*)alloc((size_t)NPAD * 64 * 2);
    float* partial = (float*)alloc((size_t)NUM_GRAPHS * PSPLIT * 64 * 4);

    // prep: zero deg + transpose weights to bf16
    k_prep<<<ZERO_GRID + PREPW_GRID, 256, 0, stream>>>(deg, Wl0, Wr0, Wl, Wr, Bt0, BtR);

    // fused: proj-GEMM | adjacency scatter (mutually independent)
    k_front<<<GEMM0_GRID + SCAT_GRID, 256, 0, stream>>>(
        x, Bt0, Ua, Va, src, dst, deg, col64);

    // 7 fused layer kernels: aggln(i) + gemm(i+1). U/V ping-pong; h in-place.
    unsigned short* Uin = Ua;  float* Vin = Va;
    unsigned short* Uout = Ub; float* Vout = Vb;
    for (int i = 0; i < 7; ++i) {
        const float* bias = (i == 0) ? bl0  : bl  + (size_t)(i - 1) * 64;
        const float* gam  = (i == 0) ? g0   : gR  + (size_t)(i - 1) * 64;
        const float* bet  = (i == 0) ? bet0 : betR + (size_t)(i - 1) * 64;
        const int have_gemm = (i < 6);
        float* hf = (i == 6) ? Vout : nullptr;   // last layer: fp32 h for pooling
        k_layer<<<GEMM0_GRID, 256, 0, stream>>>(
            Uin, Vin, hbuf, hf, deg, col64, bias, gam, bet,
            have_gemm ? (BtR + (size_t)i * 128 * 64) : BtR,
            Uout, Vout, (i > 0) ? 1 : 0, have_gemm);
        unsigned short* tu = Uin; Uin = Uout; Uout = tu;
        float* tv = Vin; Vin = Vout; Vout = tv;
    }
    float* hf_final = Vin;

    k_pool1<<<NUM_GRAPHS * PSPLIT, 256, 0, stream>>>(hf_final, batch, partial, N);
    k_head<<<1, dim3(32, 32), 0, stream>>>(partial, M0, mb0, mg0, mbe0, M, mb, mg, mbe, Wf, bf, (float*)d_out);
}

// Round 13
// 413.783 us; speedup vs baseline: 1.3495x; 1.3495x over previous
//
#include <hip/hip_runtime.h>
#include <hip/hip_bf16.h>
#include <math.h>

#define N_NODES 50000
#define N_EDGES 800000
#define NUM_GRAPHS 64
#define NPAD 50048          // multiple of 64
#define KPAD0 288           // 261 padded to multiple of 32
#define MAXDEG 64           // Poisson(16): P(deg>64) ~ 1e-20

#define GEMM0_GRID (NPAD / 64)                  // 782
#define SCAT_GRID  ((N_EDGES + 255) / 256)      // 3125
#define ZERO_GRID  ((N_NODES + 255) / 256)      // 196
#define PREPW_TOT  (128 * KPAD0 + 6 * 128 * 64) // 86016
#define PREPW_GRID ((PREPW_TOT + 255) / 256)    // 336

typedef __attribute__((ext_vector_type(8))) short short8;
typedef __attribute__((ext_vector_type(4))) float f32x4;

__device__ __forceinline__ float gelu_f(float v) {
    return 0.5f * v * (1.0f + erff(v * 0.70710678118654752440f));
}

__device__ __forceinline__ float half_sum32(float v) {
    v += __shfl_xor(v, 1); v += __shfl_xor(v, 2); v += __shfl_xor(v, 4);
    v += __shfl_xor(v, 8); v += __shfl_xor(v, 16);
    return v;
}

__device__ __forceinline__ float group_sum8(float v) {
    v += __shfl_xor(v, 1); v += __shfl_xor(v, 2); v += __shfl_xor(v, 4);
    return v;
}

__device__ __forceinline__ unsigned short f2bf(float f) {
    unsigned int u = __float_as_uint(f);
    unsigned int r = (u + 0x7fffu + ((u >> 16) & 1u)) >> 16;
    return (unsigned short)r;
}

__device__ __forceinline__ float bf_lo(unsigned int u) {
    return __uint_as_float(u << 16);
}
__device__ __forceinline__ float bf_hi(unsigned int u) {
    return __uint_as_float(u & 0xffff0000u);
}

// ---------------- prep: deg zero + pooled zero + weight transpose ----------------

__global__ void k_prep(int* __restrict__ deg, float* __restrict__ pooled,
                       const float* __restrict__ Wl0, const float* __restrict__ Wr0,
                       const float* __restrict__ Wl, const float* __restrict__ Wr,
                       unsigned short* __restrict__ Bt0, unsigned short* __restrict__ BtR) {
    const int blk = blockIdx.x, tid = threadIdx.x;
    if (blk < ZERO_GRID) {
        int i = blk * 256 + tid;
        if (i < N_NODES) deg[i] = 0;
        if (i < NUM_GRAPHS * 64) pooled[i] = 0.0f;
        return;
    }
    int idx = (blk - ZERO_GRID) * 256 + tid;
    const int n0 = 128 * KPAD0;
    if (idx < n0) {
        int j = idx / KPAD0, k = idx - j * KPAD0;
        float v = 0.0f;
        if (k < 261) v = (j < 64) ? Wl0[k * 64 + j] : Wr0[k * 64 + (j - 64)];
        Bt0[idx] = f2bf(v);
    } else if (idx < PREPW_TOT) {
        int r = idx - n0;
        int l = r >> 13;
        int rr = r & 8191;
        int j = rr >> 6, k = rr & 63;
        float v = (j < 64) ? Wl[l * 4096 + k * 64 + j] : Wr[l * 4096 + k * 64 + (j - 64)];
        BtR[r] = f2bf(v);
    }
}

// ---------------- fused front: mgemm0 | scatf (mutually independent) ----------------

__global__ __launch_bounds__(256) void k_front(
        const float* __restrict__ X, const unsigned short* __restrict__ Bt0,
        unsigned short* __restrict__ U, float* __restrict__ V,
        const int* __restrict__ src, const int* __restrict__ dst,
        int* __restrict__ deg, unsigned short* __restrict__ col64) {
    __shared__ __align__(16) unsigned short sA[64 * 32];
    __shared__ __align__(16) unsigned short sB[128 * 32];
    const int blk = blockIdx.x;
    const int tid = threadIdx.x;

    if (blk < GEMM0_GRID) {
        const int lane = tid & 63, wid = tid >> 6;
        const int l16 = lane & 15, quad = lane >> 4;
        const int m0 = blk * 64;
        f32x4 acc[8];
        #pragma unroll
        for (int j = 0; j < 8; ++j) { acc[j][0] = 0.f; acc[j][1] = 0.f; acc[j][2] = 0.f; acc[j][3] = 0.f; }
        const int arow = tid >> 2, apart = (tid & 3) << 3;
        const int node = m0 + arow;
        const int rowok = (node < N_NODES);
        for (int kc = 0; kc < KPAD0; kc += 32) {
            if (kc) __syncthreads();
            short8 av;
            #pragma unroll
            for (int j = 0; j < 8; ++j) {
                int kk = kc + apart + j;
                float val = (rowok && kk < 261) ? X[(size_t)node * 261 + kk] : 0.0f;
                av[j] = (short)f2bf(val);
            }
            *(short8*)&sA[arow * 32 + apart] = av;
            #pragma unroll
            for (int q = 0; q < 2; ++q) {
                int flat = q * 256 + tid;
                int br = flat >> 2, bp = (flat & 3) << 3;
                *(int4*)&sB[br * 32 + bp] = *(const int4*)&Bt0[(size_t)br * KPAD0 + kc + bp];
            }
            __syncthreads();
            short8 af = *(const short8*)&sA[(wid * 16 + l16) * 32 + quad * 8];
            #pragma unroll
            for (int j = 0; j < 8; ++j) {
                short8 bf = *(const short8*)&sB[(j * 16 + l16) * 32 + quad * 8];
                acc[j] = __builtin_amdgcn_mfma_f32_16x16x32_bf16(af, bf, acc[j], 0, 0, 0);
            }
        }
        const int rbase = m0 + wid * 16 + quad * 4;
        #pragma unroll
        for (int j = 0; j < 4; ++j)
            #pragma unroll
            for (int r = 0; r < 4; ++r)
                U[(size_t)(rbase + r) * 64 + j * 16 + l16] = f2bf(acc[j][r]);
        #pragma unroll
        for (int j = 4; j < 8; ++j)
            #pragma unroll
            for (int r = 0; r < 4; ++r)
                V[(size_t)(rbase + r) * 64 + (j - 4) * 16 + l16] = acc[j][r];
    } else {
        int i = (blk - GEMM0_GRID) * 256 + tid;
        if (i < N_EDGES) {
            int d = dst[i];
            int pos = atomicAdd(&deg[d], 1);
            if (pos < MAXDEG)
                __builtin_nontemporal_store((unsigned short)src[i], &col64[(d << 6) + pos]);
        }
    }
}

// ---------------- fused layer: aggln(layer i) + mgemm(layer i+1) ----------------
// Block owns 64 nodes. Phase 1: gather+LN (2 reps of 32), LN output parked in
// LDS as next GEMM A-tile. Phase 2: MFMA GEMM K=64 for next layer's U,V.
// Last layer: no h/hf writes; block-local LDS pool reduction + global atomics.

__global__ __launch_bounds__(256) void k_layer(
        const unsigned short* __restrict__ U_in, const float* __restrict__ V_in,
        unsigned short* __restrict__ h,            // in-place: residual in, LN out
        const int* __restrict__ deg, const unsigned short* __restrict__ col64,
        const float* __restrict__ bias, const float* __restrict__ gam,
        const float* __restrict__ bet,
        const unsigned short* __restrict__ Bt_next,
        unsigned short* __restrict__ U_out, float* __restrict__ V_out,
        const int* __restrict__ batch, float* __restrict__ pooled,  // pooled != null on last layer
        int residual, int have_gemm) {
    __shared__ __align__(16) unsigned short sA[2 * 64 * 32];  // [chunk][row][32k]
    __shared__ __align__(16) unsigned short sB[128 * 32];
    __shared__ float sPool[8 * 64];
    const int tid = threadIdx.x;
    const int lane = tid & 63, wid = tid >> 6;
    const int sub = lane >> 3, hl = lane & 7;
    const int base = lane & 56;
    const int m0 = blockIdx.x * 64;
    const uint4* __restrict__ Up = (const uint4*)U_in;
    const int is_last = (pooled != nullptr);

    int gmin = 0, span = 1;
    if (is_last) {
        gmin = batch[m0];
        int gmax = batch[min(m0 + 63, N_NODES - 1)];
        span = gmax - gmin + 1;
        for (int i = tid; i < 8 * 64; i += 256) sPool[i] = 0.0f;
        __syncthreads();
    }

    #pragma unroll
    for (int rep = 0; rep < 2; ++rep) {
        const int nl = rep * 32 + wid * 8 + sub;
        const int node = m0 + nl;
        const bool valid = (node < N_NODES);
        const int nd = valid ? node : 0;
        const int dg = valid ? deg[nd] : 0;
        const int cnt = min(dg, MAXDEG);
        uint4 cv = make_uint4(0u, 0u, 0u, 0u);
        if (valid) cv = *(const uint4*)&col64[((size_t)nd << 6) + hl * 8];
        float s0 = 0.f, s1 = 0.f, s2 = 0.f, s3 = 0.f, s4 = 0.f, s5 = 0.f, s6 = 0.f, s7 = 0.f;
        for (int b = 0; b * 8 < cnt; b += 2) {
            #pragma unroll
            for (int hh = 0; hh < 2; ++hh) {
                const int sl = base + b + hh;
                unsigned int p0 = (unsigned int)__shfl((int)cv.x, sl);
                unsigned int p1 = (unsigned int)__shfl((int)cv.y, sl);
                unsigned int p2 = (unsigned int)__shfl((int)cv.z, sl);
                unsigned int p3 = (unsigned int)__shfl((int)cv.w, sl);
                const int eb = (b + hh) * 8;
                int c[8];
                c[0] = (int)(p0 & 0xffffu); c[1] = (int)(p0 >> 16);
                c[2] = (int)(p1 & 0xffffu); c[3] = (int)(p1 >> 16);
                c[4] = (int)(p2 & 0xffffu); c[5] = (int)(p2 >> 16);
                c[6] = (int)(p3 & 0xffffu); c[7] = (int)(p3 >> 16);
                #pragma unroll
                for (int i = 0; i < 8; ++i) {
                    uint4 u = (eb + i < cnt) ? Up[(size_t)c[i] * 8 + hl] : make_uint4(0u, 0u, 0u, 0u);
                    s0 += bf_lo(u.x); s1 += bf_hi(u.x);
                    s2 += bf_lo(u.y); s3 += bf_hi(u.y);
                    s4 += bf_lo(u.z); s5 += bf_hi(u.z);
                    s6 += bf_lo(u.w); s7 += bf_hi(u.w);
                }
            }
        }
        const float id = 1.0f / fmaxf((float)dg, 1.0f);
        const float4 b0 = *(const float4*)&bias[8 * hl];
        const float4 b1 = *(const float4*)&bias[8 * hl + 4];
        float4 v0 = make_float4(0.f, 0.f, 0.f, 0.f), v1 = v0;
        if (valid) {
            v0 = *(const float4*)&V_in[(size_t)nd * 64 + 8 * hl];
            v1 = *(const float4*)&V_in[(size_t)nd * 64 + 8 * hl + 4];
        }
        float f0 = gelu_f(s0 * id + b0.x + v0.x);
        float f1 = gelu_f(s1 * id + b0.y + v0.y);
        float f2 = gelu_f(s2 * id + b0.z + v0.z);
        float f3 = gelu_f(s3 * id + b0.w + v0.w);
        float f4 = gelu_f(s4 * id + b1.x + v1.x);
        float f5 = gelu_f(s5 * id + b1.y + v1.y);
        float f6 = gelu_f(s6 * id + b1.z + v1.z);
        float f7 = gelu_f(s7 * id + b1.w + v1.w);
        float mu = group_sum8(((f0 + f1) + (f2 + f3)) + ((f4 + f5) + (f6 + f7))) * 0.015625f;
        float d0 = f0 - mu, d1 = f1 - mu, d2 = f2 - mu, d3 = f3 - mu;
        float d4 = f4 - mu, d5 = f5 - mu, d6 = f6 - mu, d7 = f7 - mu;
        float var = group_sum8(((d0 * d0 + d1 * d1) + (d2 * d2 + d3 * d3)) +
                               ((d4 * d4 + d5 * d5) + (d6 * d6 + d7 * d7))) * 0.015625f;
        float rs = rsqrtf(var + 1e-5f);
        const float4 g0v = *(const float4*)&gam[8 * hl];
        const float4 g1v = *(const float4*)&gam[8 * hl + 4];
        const float4 e0v = *(const float4*)&bet[8 * hl];
        const float4 e1v = *(const float4*)&bet[8 * hl + 4];
        f0 = d0 * rs * g0v.x + e0v.x;
        f1 = d1 * rs * g0v.y + e0v.y;
        f2 = d2 * rs * g0v.z + e0v.z;
        f3 = d3 * rs * g0v.w + e0v.w;
        f4 = d4 * rs * g1v.x + e1v.x;
        f5 = d5 * rs * g1v.y + e1v.y;
        f6 = d6 * rs * g1v.z + e1v.z;
        f7 = d7 * rs * g1v.w + e1v.w;
        if (residual && valid) {
            uint4 hu = ((const uint4*)h)[(size_t)nd * 8 + hl];
            f0 += bf_lo(hu.x); f1 += bf_hi(hu.x);
            f2 += bf_lo(hu.y); f3 += bf_hi(hu.y);
            f4 += bf_lo(hu.z); f5 += bf_hi(hu.z);
            f6 += bf_lo(hu.w); f7 += bf_hi(hu.w);
        }
        if (valid) {
            if (!is_last) {
                uint4 outw;
                outw.x = (unsigned int)f2bf(f0) | ((unsigned int)f2bf(f1) << 16);
                outw.y = (unsigned int)f2bf(f2) | ((unsigned int)f2bf(f3) << 16);
                outw.z = (unsigned int)f2bf(f4) | ((unsigned int)f2bf(f5) << 16);
                outw.w = (unsigned int)f2bf(f6) | ((unsigned int)f2bf(f7) << 16);
                ((uint4*)h)[(size_t)nd * 8 + hl] = outw;
                // park LN output in LDS as next-GEMM A-tile
                *(uint4*)&sA[(((hl >> 2) * 64 + nl) << 5) + (hl & 3) * 8] = outw;
            } else {
                // pooling accumulate (block-local LDS, then one flush)
                int g = batch[nd];
                if (span <= 8) {
                    float* pp = &sPool[(g - gmin) * 64 + 8 * hl];
                    atomicAdd(&pp[0], f0); atomicAdd(&pp[1], f1);
                    atomicAdd(&pp[2], f2); atomicAdd(&pp[3], f3);
                    atomicAdd(&pp[4], f4); atomicAdd(&pp[5], f5);
                    atomicAdd(&pp[6], f6); atomicAdd(&pp[7], f7);
                } else {
                    float* pp = &pooled[(size_t)g * 64 + 8 * hl];
                    atomicAdd(&pp[0], f0); atomicAdd(&pp[1], f1);
                    atomicAdd(&pp[2], f2); atomicAdd(&pp[3], f3);
                    atomicAdd(&pp[4], f4); atomicAdd(&pp[5], f5);
                    atomicAdd(&pp[6], f6); atomicAdd(&pp[7], f7);
                }
            }
        } else if (!is_last) {
            // keep sA defined for the GEMM (zero row for padding nodes)
            uint4 z = make_uint4(0u, 0u, 0u, 0u);
            *(uint4*)&sA[(((hl >> 2) * 64 + nl) << 5) + (hl & 3) * 8] = z;
        }
    }

    if (is_last) {
        __syncthreads();
        if (span <= 8) {
            for (int i = tid; i < span * 64; i += 256)
                atomicAdd(&pooled[(size_t)(gmin + (i >> 6)) * 64 + (i & 63)], sPool[i]);
        }
        return;
    }
    if (!have_gemm) return;
    __syncthreads();

    // ---- GEMM: [U_out | V_out](rows m0..m0+63) = sA @ Bt_next, K=64 ----
    const int l16 = lane & 15, quad = lane >> 4;
    f32x4 acc[8];
    #pragma unroll
    for (int j = 0; j < 8; ++j) { acc[j][0] = 0.f; acc[j][1] = 0.f; acc[j][2] = 0.f; acc[j][3] = 0.f; }
    for (int kc = 0; kc < 64; kc += 32) {
        if (kc) __syncthreads();
        #pragma unroll
        for (int q = 0; q < 2; ++q) {
            int flat = q * 256 + tid;
            int br = flat >> 2, bp = (flat & 3) << 3;
            *(int4*)&sB[br * 32 + bp] = *(const int4*)&Bt_next[(size_t)br * 64 + kc + bp];
        }
        __syncthreads();
        short8 af = *(const short8*)&sA[(((kc >> 5) * 64 + wid * 16 + l16) << 5) + quad * 8];
        #pragma unroll
        for (int j = 0; j < 8; ++j) {
            short8 bf = *(const short8*)&sB[(j * 16 + l16) * 32 + quad * 8];
            acc[j] = __builtin_amdgcn_mfma_f32_16x16x32_bf16(af, bf, acc[j], 0, 0, 0);
        }
    }
    const int rbase = m0 + wid * 16 + quad * 4;
    #pragma unroll
    for (int j = 0; j < 4; ++j)
        #pragma unroll
        for (int r = 0; r < 4; ++r)
            U_out[(size_t)(rbase + r) * 64 + j * 16 + l16] = f2bf(acc[j][r]);
    #pragma unroll
    for (int j = 4; j < 8; ++j)
        #pragma unroll
        for (int r = 0; r < 4; ++r)
            V_out[(size_t)(rbase + r) * 64 + (j - 4) * 16 + l16] = acc[j][r];
}

// ---------------- MLP head (reads pooled directly) ----------------

__global__ __launch_bounds__(1024) void k_head(const float* __restrict__ pooled,
                                               const float* __restrict__ M0, const float* __restrict__ mb0,
                                               const float* __restrict__ mg0, const float* __restrict__ mbeta0,
                                               const float* __restrict__ M, const float* __restrict__ mb,
                                               const float* __restrict__ mg, const float* __restrict__ mbeta,
                                               const float* __restrict__ Wf, const float* __restrict__ bf,
                                               float* __restrict__ out) {
    __shared__ float sP[64 * 64];
    __shared__ float sA[64 * 33];
    __shared__ float sB[64 * 33];
    const int tx = threadIdx.x, ty = threadIdx.y;
    const int tid = ty * 32 + tx;
    for (int i = tid; i < 64 * 64; i += 1024) sP[i] = pooled[i];
    __syncthreads();
    #pragma unroll
    for (int rr = 0; rr < 2; ++rr) {
        int r = ty + rr * 32;
        float a = mb0[tx];
        for (int k = 0; k < 64; ++k) a += sP[r * 64 + k] * M0[k * 32 + tx];
        a = gelu_f(a);
        float mu = half_sum32(a) * (1.0f / 32.0f);
        float d = a - mu;
        float var = half_sum32(d * d) * (1.0f / 32.0f);
        a = d * rsqrtf(var + 1e-5f) * mg0[tx] + mbeta0[tx];
        sA[r * 33 + tx] = a;
    }
    __syncthreads();
    float* cur = sA;
    float* nxt = sB;
    for (int L = 0; L < 3; ++L) {
        const float* Mi = M + L * 32 * 32;
        const float* mbi = mb + L * 32;
        const float* mgi = mg + L * 32;
        const float* mbetai = mbeta + L * 32;
        #pragma unroll
        for (int rr = 0; rr < 2; ++rr) {
            int r = ty + rr * 32;
            float a = mbi[tx];
            for (int k = 0; k < 32; ++k) a += cur[r * 33 + k] * Mi[k * 32 + tx];
            a = gelu_f(a);
            float mu = half_sum32(a) * (1.0f / 32.0f);
            float d = a - mu;
            float var = half_sum32(d * d) * (1.0f / 32.0f);
            a = d * rsqrtf(var + 1e-5f) * mgi[tx] + mbetai[tx] + cur[r * 33 + tx];
            nxt[r * 33 + tx] = a;
        }
        __syncthreads();
        float* t = cur; cur = nxt; nxt = t;
    }
    #pragma unroll
    for (int rr = 0; rr < 2; ++rr) {
        int r = ty + rr * 32;
        float p = cur[r * 33 + tx] * Wf[tx];
        p = half_sum32(p);
        if (tx == 0) out[r] = p + bf[0];
    }
}

// ---------------- host launcher ----------------

extern "C" void kernel_launch(void* const* d_in, const int* in_sizes, int n_in,
                              void* d_out, int out_size, void* d_ws, size_t ws_size,
                              hipStream_t stream) {
    const int E = N_EDGES;

    const float* x    = (const float*)d_in[0];
    const int* eidx   = (const int*)d_in[1];
    const int* batch  = (const int*)d_in[2];
    const float* Wl0  = (const float*)d_in[3];
    const float* bl0  = (const float*)d_in[4];
    const float* Wr0  = (const float*)d_in[5];
    const float* g0   = (const float*)d_in[6];
    const float* bet0 = (const float*)d_in[7];
    const float* Wl   = (const float*)d_in[8];
    const float* bl   = (const float*)d_in[9];
    const float* Wr   = (const float*)d_in[10];
    const float* gR   = (const float*)d_in[11];
    const float* betR = (const float*)d_in[12];
    const float* M0   = (const float*)d_in[13];
    const float* mb0  = (const float*)d_in[14];
    const float* mg0  = (const float*)d_in[15];
    const float* mbe0 = (const float*)d_in[16];
    const float* M    = (const float*)d_in[17];
    const float* mb   = (const float*)d_in[18];
    const float* mg   = (const float*)d_in[19];
    const float* mbe  = (const float*)d_in[20];
    const float* Wf   = (const float*)d_in[21];
    const float* bf   = (const float*)d_in[22];

    const int* src = eidx;
    const int* dst = eidx + E;

    char* p = (char*)d_ws;
    auto alloc = [&](size_t bytes) -> void* {
        void* q = (void*)p;
        p += (bytes + 255) & ~(size_t)255;
        return q;
    };
    int*   deg    = (int*)alloc((size_t)N_NODES * 4);
    unsigned short* col64 = (unsigned short*)alloc((size_t)N_NODES * MAXDEG * 2);
    unsigned short* Bt0 = (unsigned short*)alloc((size_t)128 * KPAD0 * 2);
    unsigned short* BtR = (unsigned short*)alloc((size_t)6 * 128 * 64 * 2);
    unsigned short* Ua  = (unsigned short*)alloc((size_t)NPAD * 64 * 2);
    unsigned short* Ub  = (unsigned short*)alloc((size_t)NPAD * 64 * 2);
    float* Va   = (float*)alloc((size_t)NPAD * 64 * 4);
    float* Vb   = (float*)alloc((size_t)NPAD * 64 * 4);
    unsigned short* hbuf = (unsigned short*)alloc((size_t)NPAD * 64 * 2);
    float* pooled = (float*)alloc((size_t)NUM_GRAPHS * 64 * 4);

    // prep: zero deg + pooled, transpose weights to bf16
    k_prep<<<ZERO_GRID + PREPW_GRID, 256, 0, stream>>>(deg, pooled, Wl0, Wr0, Wl, Wr, Bt0, BtR);

    // fused: proj-GEMM | adjacency scatter (mutually independent)
    k_front<<<GEMM0_GRID + SCAT_GRID, 256, 0, stream>>>(
        x, Bt0, Ua, Va, src, dst, deg, col64);

    // 7 fused layer kernels: aggln(i) + gemm(i+1); last layer fuses pooling.
    unsigned short* Uin = Ua;  float* Vin = Va;
    unsigned short* Uout = Ub; float* Vout = Vb;
    for (int i = 0; i < 7; ++i) {
        const float* bias = (i == 0) ? bl0  : bl  + (size_t)(i - 1) * 64;
        const float* gam  = (i == 0) ? g0   : gR  + (size_t)(i - 1) * 64;
        const float* bet  = (i == 0) ? bet0 : betR + (size_t)(i - 1) * 64;
        const int have_gemm = (i < 6);
        float* pool_arg = (i == 6) ? pooled : nullptr;
        k_layer<<<GEMM0_GRID, 256, 0, stream>>>(
            Uin, Vin, hbuf, deg, col64, bias, gam, bet,
            have_gemm ? (BtR + (size_t)i * 128 * 64) : BtR,
            Uout, Vout, batch, pool_arg, (i > 0) ? 1 : 0, have_gemm);
        unsigned short* tu = Uin; Uin = Uout; Uout = tu;
        float* tv = Vin; Vin = Vout; Vout = tv;
    }

    k_head<<<1, dim3(32, 32), 0, stream>>>(pooled, M0, mb0, mg0, mbe0, M, mb, mg, mbe, Wf, bf, (float*)d_out);
}

// Round 14
// 409.341 us; speedup vs baseline: 1.3641x; 1.0109x over previous
//
#include <hip/hip_runtime.h>
#include <hip/hip_bf16.h>
#include <math.h>

#define N_NODES 50000
#define N_EDGES 800000
#define NUM_GRAPHS 64
#define NPAD 50048          // multiple of 64
#define KPAD0 288           // 261 padded to multiple of 32
#define MAXDEG 64           // Poisson(16): P(deg>64) ~ 1e-20

#define GEMM0_GRID (NPAD / 64)                  // 782
#define SCAT_GRID  ((N_EDGES + 255) / 256)      // 3125
#define ZERO_GRID  ((N_NODES + 255) / 256)      // 196
#define PREPW_TOT  (128 * KPAD0 + 6 * 128 * 64) // 86016
#define PREPW_GRID ((PREPW_TOT + 255) / 256)    // 336

typedef __attribute__((ext_vector_type(8))) short short8;
typedef __attribute__((ext_vector_type(4))) float f32x4;

__device__ __forceinline__ float gelu_f(float v) {
    return 0.5f * v * (1.0f + erff(v * 0.70710678118654752440f));
}

__device__ __forceinline__ float half_sum32(float v) {
    v += __shfl_xor(v, 1); v += __shfl_xor(v, 2); v += __shfl_xor(v, 4);
    v += __shfl_xor(v, 8); v += __shfl_xor(v, 16);
    return v;
}

__device__ __forceinline__ float group_sum8(float v) {
    v += __shfl_xor(v, 1); v += __shfl_xor(v, 2); v += __shfl_xor(v, 4);
    return v;
}

__device__ __forceinline__ unsigned short f2bf(float f) {
    unsigned int u = __float_as_uint(f);
    unsigned int r = (u + 0x7fffu + ((u >> 16) & 1u)) >> 16;
    return (unsigned short)r;
}

__device__ __forceinline__ float bf_lo(unsigned int u) {
    return __uint_as_float(u << 16);
}
__device__ __forceinline__ float bf_hi(unsigned int u) {
    return __uint_as_float(u & 0xffff0000u);
}

// ---------------- prep: deg zero + pooled zero + weight transpose ----------------

__global__ void k_prep(int* __restrict__ deg, float* __restrict__ pooled,
                       const float* __restrict__ Wl0, const float* __restrict__ Wr0,
                       const float* __restrict__ Wl, const float* __restrict__ Wr,
                       unsigned short* __restrict__ Bt0, unsigned short* __restrict__ BtR) {
    const int blk = blockIdx.x, tid = threadIdx.x;
    if (blk < ZERO_GRID) {
        int i = blk * 256 + tid;
        if (i < N_NODES) deg[i] = 0;
        if (i < NUM_GRAPHS * 64) pooled[i] = 0.0f;
        return;
    }
    int idx = (blk - ZERO_GRID) * 256 + tid;
    const int n0 = 128 * KPAD0;
    if (idx < n0) {
        int j = idx / KPAD0, k = idx - j * KPAD0;
        float v = 0.0f;
        if (k < 261) v = (j < 64) ? Wl0[k * 64 + j] : Wr0[k * 64 + (j - 64)];
        Bt0[idx] = f2bf(v);
    } else if (idx < PREPW_TOT) {
        int r = idx - n0;
        int l = r >> 13;
        int rr = r & 8191;
        int j = rr >> 6, k = rr & 63;
        float v = (j < 64) ? Wl[l * 4096 + k * 64 + j] : Wr[l * 4096 + k * 64 + (j - 64)];
        BtR[r] = f2bf(v);
    }
}

// ---------------- fused front: mgemm0 | scatf (mutually independent) ----------------

__global__ __launch_bounds__(256) void k_front(
        const float* __restrict__ X, const unsigned short* __restrict__ Bt0,
        unsigned short* __restrict__ U, float* __restrict__ V,
        const int* __restrict__ src, const int* __restrict__ dst,
        int* __restrict__ deg, unsigned short* __restrict__ col64) {
    __shared__ __align__(16) unsigned short sA[64 * 32];
    __shared__ __align__(16) unsigned short sB[128 * 32];
    const int blk = blockIdx.x;
    const int tid = threadIdx.x;

    if (blk < GEMM0_GRID) {
        const int lane = tid & 63, wid = tid >> 6;
        const int l16 = lane & 15, quad = lane >> 4;
        const int m0 = blk * 64;
        f32x4 acc[8];
        #pragma unroll
        for (int j = 0; j < 8; ++j) { acc[j][0] = 0.f; acc[j][1] = 0.f; acc[j][2] = 0.f; acc[j][3] = 0.f; }
        const int arow = tid >> 2, apart = (tid & 3) << 3;
        const int node = m0 + arow;
        const int rowok = (node < N_NODES);
        for (int kc = 0; kc < KPAD0; kc += 32) {
            if (kc) __syncthreads();
            short8 av;
            #pragma unroll
            for (int j = 0; j < 8; ++j) {
                int kk = kc + apart + j;
                float val = (rowok && kk < 261) ? X[(size_t)node * 261 + kk] : 0.0f;
                av[j] = (short)f2bf(val);
            }
            *(short8*)&sA[arow * 32 + apart] = av;
            #pragma unroll
            for (int q = 0; q < 2; ++q) {
                int flat = q * 256 + tid;
                int br = flat >> 2, bp = (flat & 3) << 3;
                *(int4*)&sB[br * 32 + bp] = *(const int4*)&Bt0[(size_t)br * KPAD0 + kc + bp];
            }
            __syncthreads();
            short8 af = *(const short8*)&sA[(wid * 16 + l16) * 32 + quad * 8];
            #pragma unroll
            for (int j = 0; j < 8; ++j) {
                short8 bf = *(const short8*)&sB[(j * 16 + l16) * 32 + quad * 8];
                acc[j] = __builtin_amdgcn_mfma_f32_16x16x32_bf16(af, bf, acc[j], 0, 0, 0);
            }
        }
        const int rbase = m0 + wid * 16 + quad * 4;
        #pragma unroll
        for (int j = 0; j < 4; ++j)
            #pragma unroll
            for (int r = 0; r < 4; ++r)
                U[(size_t)(rbase + r) * 64 + j * 16 + l16] = f2bf(acc[j][r]);
        #pragma unroll
        for (int j = 4; j < 8; ++j)
            #pragma unroll
            for (int r = 0; r < 4; ++r)
                V[(size_t)(rbase + r) * 64 + (j - 4) * 16 + l16] = acc[j][r];
    } else {
        int i = (blk - GEMM0_GRID) * 256 + tid;
        if (i < N_EDGES) {
            int d = dst[i];
            int pos = atomicAdd(&deg[d], 1);
            if (pos < MAXDEG) col64[(d << 6) + pos] = (unsigned short)src[i];
        }
    }
}

// ---------------- per-block degree-sort: slot -> local node id ----------------
// Waves' concurrently-executing sub-groups get near-equal degrees, cutting the
// max-of-8 divergence in the gather loop (~2.1x -> ~1.45x iterations).

__global__ __launch_bounds__(64) void k_sortperm(const int* __restrict__ deg,
                                                 unsigned char* __restrict__ perm) {
    __shared__ int sk[64];
    const int t = threadIdx.x;
    const int m0 = blockIdx.x * 64;
    const int node = m0 + t;
    int d = (node < N_NODES) ? deg[node] : 0;
    sk[t] = (d << 6) | t;
    __syncthreads();
    for (int k = 2; k <= 64; k <<= 1) {
        for (int j = k >> 1; j > 0; j >>= 1) {
            int ixj = t ^ j;
            if (ixj > t) {
                int a = sk[t], b = sk[ixj];
                bool up = ((t & k) == 0);
                if ((a > b) == up) { sk[t] = b; sk[ixj] = a; }
            }
            __syncthreads();
        }
    }
    perm[m0 + t] = (unsigned char)(sk[t] & 63);
}

// ---------------- fused layer: aggln(layer i) + mgemm(layer i+1) ----------------
// Block owns 64 nodes. Phase 1: gather+LN (2 reps of 32, degree-sorted slot
// assignment), LN output parked in LDS as next GEMM A-tile. Phase 2: MFMA GEMM
// K=64 for next layer's U,V. Last layer: fused pooling via LDS + atomics.

__global__ __launch_bounds__(256) void k_layer(
        const unsigned short* __restrict__ U_in, const float* __restrict__ V_in,
        unsigned short* __restrict__ h,            // in-place: residual in, LN out
        const int* __restrict__ deg, const unsigned short* __restrict__ col64,
        const unsigned char* __restrict__ perm,
        const float* __restrict__ bias, const float* __restrict__ gam,
        const float* __restrict__ bet,
        const unsigned short* __restrict__ Bt_next,
        unsigned short* __restrict__ U_out, float* __restrict__ V_out,
        const int* __restrict__ batch, float* __restrict__ pooled,  // pooled != null on last layer
        int residual, int have_gemm) {
    __shared__ __align__(16) unsigned short sA[2 * 64 * 32];  // [chunk][row][32k]
    __shared__ __align__(16) unsigned short sB[128 * 32];
    __shared__ float sPool[8 * 64];
    const int tid = threadIdx.x;
    const int lane = tid & 63, wid = tid >> 6;
    const int sub = lane >> 3, hl = lane & 7;
    const int base = lane & 56;
    const int m0 = blockIdx.x * 64;
    const uint4* __restrict__ Up = (const uint4*)U_in;
    const int is_last = (pooled != nullptr);

    int gmin = 0, span = 1;
    if (is_last) {
        gmin = batch[m0];
        int gmax = batch[min(m0 + 63, N_NODES - 1)];
        span = gmax - gmin + 1;
        for (int i = tid; i < 8 * 64; i += 256) sPool[i] = 0.0f;
        __syncthreads();
    }

    const int idx0 = wid * 8 + sub;   // 0..31

    #pragma unroll
    for (int rep = 0; rep < 2; ++rep) {
        // rep0: sorted ranks 0..31 ascending; rep1: ranks 63..32 (balances wave sums)
        const int rank = (rep == 0) ? idx0 : (63 - idx0);
        const int nl = perm[m0 + rank];
        const int node = m0 + nl;
        const bool valid = (node < N_NODES);
        const int nd = valid ? node : 0;
        const int dg = valid ? deg[nd] : 0;
        const int cnt = min(dg, MAXDEG);
        uint4 cv = make_uint4(0u, 0u, 0u, 0u);
        if (valid) cv = *(const uint4*)&col64[((size_t)nd << 6) + hl * 8];
        float s0 = 0.f, s1 = 0.f, s2 = 0.f, s3 = 0.f, s4 = 0.f, s5 = 0.f, s6 = 0.f, s7 = 0.f;
        for (int b = 0; b * 8 < cnt; b += 2) {
            #pragma unroll
            for (int hh = 0; hh < 2; ++hh) {
                const int sl = base + b + hh;
                unsigned int p0 = (unsigned int)__shfl((int)cv.x, sl);
                unsigned int p1 = (unsigned int)__shfl((int)cv.y, sl);
                unsigned int p2 = (unsigned int)__shfl((int)cv.z, sl);
                unsigned int p3 = (unsigned int)__shfl((int)cv.w, sl);
                const int eb = (b + hh) * 8;
                int c[8];
                c[0] = (int)(p0 & 0xffffu); c[1] = (int)(p0 >> 16);
                c[2] = (int)(p1 & 0xffffu); c[3] = (int)(p1 >> 16);
                c[4] = (int)(p2 & 0xffffu); c[5] = (int)(p2 >> 16);
                c[6] = (int)(p3 & 0xffffu); c[7] = (int)(p3 >> 16);
                #pragma unroll
                for (int i = 0; i < 8; ++i) {
                    uint4 u = (eb + i < cnt) ? Up[(size_t)c[i] * 8 + hl] : make_uint4(0u, 0u, 0u, 0u);
                    s0 += bf_lo(u.x); s1 += bf_hi(u.x);
                    s2 += bf_lo(u.y); s3 += bf_hi(u.y);
                    s4 += bf_lo(u.z); s5 += bf_hi(u.z);
                    s6 += bf_lo(u.w); s7 += bf_hi(u.w);
                }
            }
        }
        const float id = 1.0f / fmaxf((float)dg, 1.0f);
        const float4 b0 = *(const float4*)&bias[8 * hl];
        const float4 b1 = *(const float4*)&bias[8 * hl + 4];
        float4 v0 = make_float4(0.f, 0.f, 0.f, 0.f), v1 = v0;
        if (valid) {
            v0 = *(const float4*)&V_in[(size_t)nd * 64 + 8 * hl];
            v1 = *(const float4*)&V_in[(size_t)nd * 64 + 8 * hl + 4];
        }
        float f0 = gelu_f(s0 * id + b0.x + v0.x);
        float f1 = gelu_f(s1 * id + b0.y + v0.y);
        float f2 = gelu_f(s2 * id + b0.z + v0.z);
        float f3 = gelu_f(s3 * id + b0.w + v0.w);
        float f4 = gelu_f(s4 * id + b1.x + v1.x);
        float f5 = gelu_f(s5 * id + b1.y + v1.y);
        float f6 = gelu_f(s6 * id + b1.z + v1.z);
        float f7 = gelu_f(s7 * id + b1.w + v1.w);
        float mu = group_sum8(((f0 + f1) + (f2 + f3)) + ((f4 + f5) + (f6 + f7))) * 0.015625f;
        float d0 = f0 - mu, d1 = f1 - mu, d2 = f2 - mu, d3 = f3 - mu;
        float d4 = f4 - mu, d5 = f5 - mu, d6 = f6 - mu, d7 = f7 - mu;
        float var = group_sum8(((d0 * d0 + d1 * d1) + (d2 * d2 + d3 * d3)) +
                               ((d4 * d4 + d5 * d5) + (d6 * d6 + d7 * d7))) * 0.015625f;
        float rs = rsqrtf(var + 1e-5f);
        const float4 g0v = *(const float4*)&gam[8 * hl];
        const float4 g1v = *(const float4*)&gam[8 * hl + 4];
        const float4 e0v = *(const float4*)&bet[8 * hl];
        const float4 e1v = *(const float4*)&bet[8 * hl + 4];
        f0 = d0 * rs * g0v.x + e0v.x;
        f1 = d1 * rs * g0v.y + e0v.y;
        f2 = d2 * rs * g0v.z + e0v.z;
        f3 = d3 * rs * g0v.w + e0v.w;
        f4 = d4 * rs * g1v.x + e1v.x;
        f5 = d5 * rs * g1v.y + e1v.y;
        f6 = d6 * rs * g1v.z + e1v.z;
        f7 = d7 * rs * g1v.w + e1v.w;
        if (residual && valid) {
            uint4 hu = ((const uint4*)h)[(size_t)nd * 8 + hl];
            f0 += bf_lo(hu.x); f1 += bf_hi(hu.x);
            f2 += bf_lo(hu.y); f3 += bf_hi(hu.y);
            f4 += bf_lo(hu.z); f5 += bf_hi(hu.z);
            f6 += bf_lo(hu.w); f7 += bf_hi(hu.w);
        }
        if (valid) {
            if (!is_last) {
                uint4 outw;
                outw.x = (unsigned int)f2bf(f0) | ((unsigned int)f2bf(f1) << 16);
                outw.y = (unsigned int)f2bf(f2) | ((unsigned int)f2bf(f3) << 16);
                outw.z = (unsigned int)f2bf(f4) | ((unsigned int)f2bf(f5) << 16);
                outw.w = (unsigned int)f2bf(f6) | ((unsigned int)f2bf(f7) << 16);
                ((uint4*)h)[(size_t)nd * 8 + hl] = outw;
                *(uint4*)&sA[(((hl >> 2) * 64 + nl) << 5) + (hl & 3) * 8] = outw;
            } else {
                int g = batch[nd];
                if (span <= 8) {
                    float* pp = &sPool[(g - gmin) * 64 + 8 * hl];
                    atomicAdd(&pp[0], f0); atomicAdd(&pp[1], f1);
                    atomicAdd(&pp[2], f2); atomicAdd(&pp[3], f3);
                    atomicAdd(&pp[4], f4); atomicAdd(&pp[5], f5);
                    atomicAdd(&pp[6], f6); atomicAdd(&pp[7], f7);
                } else {
                    float* pp = &pooled[(size_t)g * 64 + 8 * hl];
                    atomicAdd(&pp[0], f0); atomicAdd(&pp[1], f1);
                    atomicAdd(&pp[2], f2); atomicAdd(&pp[3], f3);
                    atomicAdd(&pp[4], f4); atomicAdd(&pp[5], f5);
                    atomicAdd(&pp[6], f6); atomicAdd(&pp[7], f7);
                }
            }
        } else if (!is_last) {
            uint4 z = make_uint4(0u, 0u, 0u, 0u);
            *(uint4*)&sA[(((hl >> 2) * 64 + nl) << 5) + (hl & 3) * 8] = z;
        }
    }

    if (is_last) {
        __syncthreads();
        if (span <= 8) {
            for (int i = tid; i < span * 64; i += 256)
                atomicAdd(&pooled[(size_t)(gmin + (i >> 6)) * 64 + (i & 63)], sPool[i]);
        }
        return;
    }
    if (!have_gemm) return;
    __syncthreads();

    // ---- GEMM: [U_out | V_out](rows m0..m0+63) = sA @ Bt_next, K=64 ----
    const int l16 = lane & 15, quad = lane >> 4;
    f32x4 acc[8];
    #pragma unroll
    for (int j = 0; j < 8; ++j) { acc[j][0] = 0.f; acc[j][1] = 0.f; acc[j][2] = 0.f; acc[j][3] = 0.f; }
    for (int kc = 0; kc < 64; kc += 32) {
        if (kc) __syncthreads();
        #pragma unroll
        for (int q = 0; q < 2; ++q) {
            int flat = q * 256 + tid;
            int br = flat >> 2, bp = (flat & 3) << 3;
            *(int4*)&sB[br * 32 + bp] = *(const int4*)&Bt_next[(size_t)br * 64 + kc + bp];
        }
        __syncthreads();
        short8 af = *(const short8*)&sA[(((kc >> 5) * 64 + wid * 16 + l16) << 5) + quad * 8];
        #pragma unroll
        for (int j = 0; j < 8; ++j) {
            short8 bf = *(const short8*)&sB[(j * 16 + l16) * 32 + quad * 8];
            acc[j] = __builtin_amdgcn_mfma_f32_16x16x32_bf16(af, bf, acc[j], 0, 0, 0);
        }
    }
    const int rbase = m0 + wid * 16 + quad * 4;
    #pragma unroll
    for (int j = 0; j < 4; ++j)
        #pragma unroll
        for (int r = 0; r < 4; ++r)
            U_out[(size_t)(rbase + r) * 64 + j * 16 + l16] = f2bf(acc[j][r]);
    #pragma unroll
    for (int j = 4; j < 8; ++j)
        #pragma unroll
        for (int r = 0; r < 4; ++r)
            V_out[(size_t)(rbase + r) * 64 + (j - 4) * 16 + l16] = acc[j][r];
}

// ---------------- MLP head (reads pooled directly) ----------------

__global__ __launch_bounds__(1024) void k_head(const float* __restrict__ pooled,
                                               const float* __restrict__ M0, const float* __restrict__ mb0,
                                               const float* __restrict__ mg0, const float* __restrict__ mbeta0,
                                               const float* __restrict__ M, const float* __restrict__ mb,
                                               const float* __restrict__ mg, const float* __restrict__ mbeta,
                                               const float* __restrict__ Wf, const float* __restrict__ bf,
                                               float* __restrict__ out) {
    __shared__ float sP[64 * 64];
    __shared__ float sA[64 * 33];
    __shared__ float sB[64 * 33];
    const int tx = threadIdx.x, ty = threadIdx.y;
    const int tid = ty * 32 + tx;
    for (int i = tid; i < 64 * 64; i += 1024) sP[i] = pooled[i];
    __syncthreads();
    #pragma unroll
    for (int rr = 0; rr < 2; ++rr) {
        int r = ty + rr * 32;
        float a = mb0[tx];
        for (int k = 0; k < 64; ++k) a += sP[r * 64 + k] * M0[k * 32 + tx];
        a = gelu_f(a);
        float mu = half_sum32(a) * (1.0f / 32.0f);
        float d = a - mu;
        float var = half_sum32(d * d) * (1.0f / 32.0f);
        a = d * rsqrtf(var + 1e-5f) * mg0[tx] + mbeta0[tx];
        sA[r * 33 + tx] = a;
    }
    __syncthreads();
    float* cur = sA;
    float* nxt = sB;
    for (int L = 0; L < 3; ++L) {
        const float* Mi = M + L * 32 * 32;
        const float* mbi = mb + L * 32;
        const float* mgi = mg + L * 32;
        const float* mbetai = mbeta + L * 32;
        #pragma unroll
        for (int rr = 0; rr < 2; ++rr) {
            int r = ty + rr * 32;
            float a = mbi[tx];
            for (int k = 0; k < 32; ++k) a += cur[r * 33 + k] * Mi[k * 32 + tx];
            a = gelu_f(a);
            float mu = half_sum32(a) * (1.0f / 32.0f);
            float d = a - mu;
            float var = half_sum32(d * d) * (1.0f / 32.0f);
            a = d * rsqrtf(var + 1e-5f) * mgi[tx] + mbetai[tx] + cur[r * 33 + tx];
            nxt[r * 33 + tx] = a;
        }
        __syncthreads();
        float* t = cur; cur = nxt; nxt = t;
    }
    #pragma unroll
    for (int rr = 0; rr < 2; ++rr) {
        int r = ty + rr * 32;
        float p = cur[r * 33 + tx] * Wf[tx];
        p = half_sum32(p);
        if (tx == 0) out[r] = p + bf[0];
    }
}

// ---------------- host launcher ----------------

extern "C" void kernel_launch(void* const* d_in, const int* in_sizes, int n_in,
                              void* d_out, int out_size, void* d_ws, size_t ws_size,
                              hipStream_t stream) {
    const int E = N_EDGES;

    const float* x    = (const float*)d_in[0];
    const int* eidx   = (const int*)d_in[1];
    const int* batch  = (const int*)d_in[2];
    const float* Wl0  = (const float*)d_in[3];
    const float* bl0  = (const float*)d_in[4];
    const float* Wr0  = (const float*)d_in[5];
    const float* g0   = (const float*)d_in[6];
    const float* bet0 = (const float*)d_in[7];
    const float* Wl   = (const float*)d_in[8];
    const float* bl   = (const float*)d_in[9];
    const float* Wr   = (const float*)d_in[10];
    const float* gR   = (const float*)d_in[11];
    const float* betR = (const float*)d_in[12];
    const float* M0   = (const float*)d_in[13];
    const float* mb0  = (const float*)d_in[14];
    const float* mg0  = (const float*)d_in[15];
    const float* mbe0 = (const float*)d_in[16];
    const float* M    = (const float*)d_in[17];
    const float* mb   = (const float*)d_in[18];
    const float* mg   = (const float*)d_in[19];
    const float* mbe  = (const float*)d_in[20];
    const float* Wf   = (const float*)d_in[21];
    const float* bf   = (const float*)d_in[22];

    const int* src = eidx;
    const int* dst = eidx + E;

    char* p = (char*)d_ws;
    auto alloc = [&](size_t bytes) -> void* {
        void* q = (void*)p;
        p += (bytes + 255) & ~(size_t)255;
        return q;
    };
    int*   deg    = (int*)alloc((size_t)N_NODES * 4);
    unsigned short* col64 = (unsigned short*)alloc((size_t)N_NODES * MAXDEG * 2);
    unsigned char* perm = (unsigned char*)alloc((size_t)NPAD);
    unsigned short* Bt0 = (unsigned short*)alloc((size_t)128 * KPAD0 * 2);
    unsigned short* BtR = (unsigned short*)alloc((size_t)6 * 128 * 64 * 2);
    unsigned short* Ua  = (unsigned short*)alloc((size_t)NPAD * 64 * 2);
    unsigned short* Ub  = (unsigned short*)alloc((size_t)NPAD * 64 * 2);
    float* Va   = (float*)alloc((size_t)NPAD * 64 * 4);
    float* Vb   = (float*)alloc((size_t)NPAD * 64 * 4);
    unsigned short* hbuf = (unsigned short*)alloc((size_t)NPAD * 64 * 2);
    float* pooled = (float*)alloc((size_t)NUM_GRAPHS * 64 * 4);

    // prep: zero deg + pooled, transpose weights to bf16
    k_prep<<<ZERO_GRID + PREPW_GRID, 256, 0, stream>>>(deg, pooled, Wl0, Wr0, Wl, Wr, Bt0, BtR);

    // fused: proj-GEMM | adjacency scatter (mutually independent)
    k_front<<<GEMM0_GRID + SCAT_GRID, 256, 0, stream>>>(
        x, Bt0, Ua, Va, src, dst, deg, col64);

    // per-block degree sort (deg final after k_front)
    k_sortperm<<<GEMM0_GRID, 64, 0, stream>>>(deg, perm);

    // 7 fused layer kernels: aggln(i) + gemm(i+1); last layer fuses pooling.
    unsigned short* Uin = Ua;  float* Vin = Va;
    unsigned short* Uout = Ub; float* Vout = Vb;
    for (int i = 0; i < 7; ++i) {
        const float* bias = (i == 0) ? bl0  : bl  + (size_t)(i - 1) * 64;
        const float* gam  = (i == 0) ? g0   : gR  + (size_t)(i - 1) * 64;
        const float* bet  = (i == 0) ? bet0 : betR + (size_t)(i - 1) * 64;
        const int have_gemm = (i < 6);
        float* pool_arg = (i == 6) ? pooled : nullptr;
        k_layer<<<GEMM0_GRID, 256, 0, stream>>>(
            Uin, Vin, hbuf, deg, col64, perm, bias, gam, bet,
            have_gemm ? (BtR + (size_t)i * 128 * 64) : BtR,
            Uout, Vout, batch, pool_arg, (i > 0) ? 1 : 0, have_gemm);
        unsigned short* tu = Uin; Uin = Uout; Uout = tu;
        float* tv = Vin; Vin = Vout; Vout = tv;
    }

    k_head<<<1, dim3(32, 32), 0, stream>>>(pooled, M0, mb0, mg0, mbe0, M, mb, mg, mbe, Wf, bf, (float*)d_out);
}